// Round 7
// baseline (148.558 us; speedup 1.0000x reference)
//
#include <hip/hip_runtime.h>
#include <math.h>

// Dims fixed by reference setup_inputs
#define B_ 4
#define S_ 2048
#define D_ 1024
#define G_ 512
#define T_ 2047          // diff rows per batch
#define R_ 8188          // B_*T_ valid rows
#define RPAD 8192
#define MT 32            // diff rows per fused block
#define AST1 1040        // gemm1 A LDS stride (shorts): 1024 + 16 pad
#define AST2 528         // gemm2 A (weights) LDS stride (shorts): 512 + 16 pad

typedef __attribute__((ext_vector_type(8))) short short8;
typedef __attribute__((ext_vector_type(4))) short s16x4;
typedef __attribute__((ext_vector_type(16))) float f32x16;

// ws byte offsets
#define WSOFF_RG2  0u           // 512 f
#define WSOFF_MAGW 2048u        // 8192 f
#define WSOFF_BP1  34816u       // Bpack1 [128][512] short8 (1 MB)
#define WSOFF_BP2  1083392u     // Bpack2 [64][1024] short8 (1 MB)
#define WSOFF_NH   2131968u     // normh [8192][1024] bf16 (16 MB)
#define WSOFF_IH   18909184u    // inflh [8192][1024] bf16 (16 MB)

// dynamic LDS layout (bytes)
#define LDS_AB    0u            // short[32][1040] = 66560 B (aliased: short[32][528] weights)
#define LDS_RG2   66560u        // 512 f
#define LDS_PRED  68608u        // 32*16 f
#define LDS_RMX   70656u        // 32 f
#define LDS_RRS   70784u        // 32 f
#define LDS_TOTAL 70912u

__device__ inline short to_bf16(float f) {
    union { float f; unsigned u; } v; v.f = f;
    unsigned r = v.u + 0x7fffu + ((v.u >> 16) & 1u);
    return (short)(r >> 16);
}
__device__ inline float fb(unsigned short h) {
    union { unsigned u; float f; } v;
    v.u = ((unsigned)h) << 16;
    return v.f;
}

// ---------------------------------------------------------------------------
// prep: blocks 0..127  -> rg2 + Bpack1 (4 g-rows per block, one wave each)
//       blocks 128..383 -> Bpack2
// ---------------------------------------------------------------------------
__global__ __launch_bounds__(256) void prep_kernel(const float* __restrict__ guid,
                                                   float* __restrict__ rg2,
                                                   short8* __restrict__ Bp1,
                                                   short8* __restrict__ Bp2) {
    int blk = blockIdx.x, tid = threadIdx.x;
    if (blk < 128) {
        int g = blk * 4 + (tid >> 6);
        int lane = tid & 63;
        const float4* gp = (const float4*)(guid + (size_t)g * D_);
        float ss = 0.f;
#pragma unroll
        for (int i = 0; i < 4; ++i) {
            float4 v = gp[lane + 64 * i];
            ss += v.x * v.x + v.y * v.y + v.z * v.z + v.w * v.w;
        }
#pragma unroll
        for (int m = 32; m >= 1; m >>= 1) ss += __shfl_xor(ss, m, 64);
        if (lane == 0) rg2[g] = 2.0f / fmaxf(sqrtf(ss), 1e-8f);
#pragma unroll
        for (int h = 0; h < 2; ++h) {
            int kg = lane + 64 * h;
            const float* src = guid + (size_t)g * D_ + kg * 8;
            short8 v;
#pragma unroll
            for (int j = 0; j < 8; ++j) v[j] = to_bf16(src[j]);
            Bp1[(size_t)kg * G_ + g] = v;
        }
    } else {
        int idx = blk - 128;
        int gg = idx >> 2;
        int d = (idx & 3) * 256 + tid;
        short8 v;
#pragma unroll
        for (int j = 0; j < 8; ++j) v[j] = to_bf16(guid[(size_t)(gg * 8 + j) * D_ + d]);
        Bp2[(size_t)gg * D_ + d] = v;
    }
}

// ---------------------------------------------------------------------------
// fused: 32-row tile, 16 waves, 32x32x16 MFMA.
//   diff/norm -> full-K A in dynamic LDS -> gemm1 (64 steps, depth-4 B
//   prefetch) -> softmax -> weights in LDS -> gemm2 (32 steps, depth-2) ->
//   normh/inflh bf16.
// A-frag layout (32x32x16): A[m=lane&31][k=(lane>>5)*8+j]  (16-B ds_read)
// B-frag: Bp[kg=2*ks+(lane>>5)][n] with n=g/d col — existing packing fits.
// C/D: col=lane&31, row=(reg&3)+8*(reg>>2)+4*(lane>>5)  [m74/m101 verified]
// ---------------------------------------------------------------------------
__global__ __launch_bounds__(1024, 4) void fused_kernel(const float* __restrict__ emb,
                                                        const short8* __restrict__ Bp1,
                                                        const short8* __restrict__ Bp2,
                                                        const float* __restrict__ rg2,
                                                        float* __restrict__ magw,
                                                        short* __restrict__ normh,
                                                        short* __restrict__ inflh) {
    extern __shared__ char smem[];
    short* ABs  = (short*)(smem + LDS_AB);    // stride AST1 (gemm1 A)
    short* WBs  = (short*)(smem + LDS_AB);    // stride AST2 (gemm2 A, aliased)
    float* rg2s = (float*)(smem + LDS_RG2);
    float* pred = (float*)(smem + LDS_PRED);  // [32][16]
    float* rmx  = (float*)(smem + LDS_RMX);
    float* rrs  = (float*)(smem + LDS_RRS);

    const int tid = threadIdx.x;
    const int wave = tid >> 6, lane = tid & 63;
    const int l31 = lane & 31, half = lane >> 5;
    const int r0 = blockIdx.x * MT;

    if (tid < G_) rg2s[tid] = rg2[tid];

    // ---- Phase 1: diff + normalize, 2 rows/wave; full K row -> LDS ----
#pragma unroll
    for (int i = 0; i < 2; ++i) {
        int rr = wave * 2 + i;
        int R = r0 + rr;
        if (R < R_) {
            int b = R / T_;
            int t = R - b * T_;
            const float4* p = (const float4*)(emb + ((size_t)b * S_ + t) * D_);
            float4 dv[4]; float ss = 0.f;
#pragma unroll
            for (int j = 0; j < 4; ++j) {
                float4 x0 = p[lane + 64 * j];
                float4 x1 = p[lane + 64 * j + 256];
                dv[j] = make_float4(x1.x - x0.x, x1.y - x0.y, x1.z - x0.z, x1.w - x0.w);
                ss += dv[j].x * dv[j].x + dv[j].y * dv[j].y + dv[j].z * dv[j].z + dv[j].w * dv[j].w;
            }
#pragma unroll
            for (int m = 32; m >= 1; m >>= 1) ss += __shfl_xor(ss, m, 64);
            float mag = sqrtf(ss);
            float rmag = (mag > 1e-6f) ? (1.0f / mag) : 0.0f;
            if (lane == 0) magw[R] = tanhf(2.0f * mag);
            s16x4 h[4];
#pragma unroll
            for (int j = 0; j < 4; ++j) {
                h[j][0] = to_bf16(dv[j].x * rmag); h[j][1] = to_bf16(dv[j].y * rmag);
                h[j][2] = to_bf16(dv[j].z * rmag); h[j][3] = to_bf16(dv[j].w * rmag);
            }
            short* nb = normh + (size_t)R * D_ + 4 * lane;
#pragma unroll
            for (int j = 0; j < 4; ++j) *(s16x4*)(nb + 256 * j) = h[j];
#pragma unroll
            for (int j = 0; j < 4; ++j) *(s16x4*)&ABs[rr * AST1 + 4 * lane + 256 * j] = h[j];
        } else {
            s16x4 z = (s16x4)0;
#pragma unroll
            for (int j = 0; j < 4; ++j) *(s16x4*)&ABs[rr * AST1 + 4 * lane + 256 * j] = z;
        }
    }
    __syncthreads();

    // ---- Phase 2: gemm1, wave owns g in [32w, 32w+32); 64 k-steps ----
    f32x16 acc1 = (f32x16)0.f;
    {
        const int g0 = wave * 32;
        const short8* Bb = Bp1 + (size_t)half * G_ + g0 + l31;
        const short* Arow = &ABs[l31 * AST1 + half * 8];
        short8 bbuf[4];
#pragma unroll
        for (int i = 0; i < 4; ++i) bbuf[i] = Bb[(size_t)(2 * i) * G_];
#pragma unroll
        for (int ks = 0; ks < 64; ++ks) {
            short8 a = *(const short8*)(Arow + ks * 16);
            short8 b = bbuf[ks & 3];
            if (ks < 60) bbuf[ks & 3] = Bb[(size_t)(2 * (ks + 4)) * G_];
            acc1 = __builtin_amdgcn_mfma_f32_32x32x16_bf16(a, b, acc1, 0, 0, 0);
        }
    }

    // ---- Phase 3: softmax over g (rows per reg: (r&3)+8*(r>>2)+4*half) ----
    {
        const int g0 = wave * 32;
        float rgv = rg2s[g0 + l31];
        float lg[16];
#pragma unroll
        for (int r = 0; r < 16; ++r) lg[r] = acc1[r] * rgv;
        // per-row max within the half (32 lanes hold the row's 32 g)
        float pm[16];
#pragma unroll
        for (int r = 0; r < 16; ++r) pm[r] = lg[r];
#pragma unroll
        for (int m = 16; m >= 1; m >>= 1)
#pragma unroll
            for (int r = 0; r < 16; ++r) pm[r] = fmaxf(pm[r], __shfl_xor(pm[r], m, 64));
        if (l31 == 0) {
#pragma unroll
            for (int r = 0; r < 16; ++r) {
                int row = (r & 3) + 8 * (r >> 2) + 4 * half;
                pred[row * 16 + wave] = pm[r];
            }
        }
        __syncthreads();
        if (tid < MT) {
            float m = pred[tid * 16];
#pragma unroll
            for (int w2 = 1; w2 < 16; ++w2) m = fmaxf(m, pred[tid * 16 + w2]);
            rmx[tid] = m;
        }
        __syncthreads();
        float ps[16];
#pragma unroll
        for (int r = 0; r < 16; ++r) {
            int row = (r & 3) + 8 * (r >> 2) + 4 * half;
            float e = __expf(lg[r] - rmx[row]);
            lg[r] = e;
            ps[r] = e;
        }
#pragma unroll
        for (int m = 16; m >= 1; m >>= 1)
#pragma unroll
            for (int r = 0; r < 16; ++r) ps[r] += __shfl_xor(ps[r], m, 64);
        if (l31 == 0) {
#pragma unroll
            for (int r = 0; r < 16; ++r) {
                int row = (r & 3) + 8 * (r >> 2) + 4 * half;
                pred[row * 16 + wave] = ps[r];
            }
        }
        __syncthreads();
        if (tid < MT) {
            float s = 0.f;
#pragma unroll
            for (int w2 = 0; w2 < 16; ++w2) s += pred[tid * 16 + w2];
            rrs[tid] = 1.0f / s;
        }
        __syncthreads();
        // weights -> WBs (stride AST2); AB region no longer needed as gemm1 A
#pragma unroll
        for (int r = 0; r < 16; ++r) {
            int row = (r & 3) + 8 * (r >> 2) + 4 * half;
            WBs[row * AST2 + g0 + l31] = to_bf16(lg[r] * rrs[row]);
        }
    }
    __syncthreads();

    // ---- Phase 4: gemm2, wave owns d in [64w, 64w+64); 32 k-steps ----
    f32x16 acc2[2];
    acc2[0] = (f32x16)0.f; acc2[1] = (f32x16)0.f;
    {
        const int d0 = wave * 64;
        const short8* Bb = Bp2 + (size_t)half * D_ + d0 + l31;
        const short* Arow = &WBs[l31 * AST2 + half * 8];
        short8 bbuf[2][2];
#pragma unroll
        for (int i = 0; i < 2; ++i) {
            bbuf[i][0] = Bb[(size_t)(2 * i) * D_];
            bbuf[i][1] = Bb[(size_t)(2 * i) * D_ + 32];
        }
#pragma unroll
        for (int ks = 0; ks < 32; ++ks) {
            short8 a = *(const short8*)(Arow + ks * 16);
            short8 b0 = bbuf[ks & 1][0], b1 = bbuf[ks & 1][1];
            if (ks < 30) {
                const short8* Bx = Bb + (size_t)(2 * (ks + 2)) * D_;
                bbuf[ks & 1][0] = Bx[0]; bbuf[ks & 1][1] = Bx[32];
            }
            acc2[0] = __builtin_amdgcn_mfma_f32_32x32x16_bf16(a, b0, acc2[0], 0, 0, 0);
            acc2[1] = __builtin_amdgcn_mfma_f32_32x32x16_bf16(a, b1, acc2[1], 0, 0, 0);
        }
    }

    // ---- Phase 5: influence bf16 out ----
    {
        const int d0 = wave * 64;
#pragma unroll
        for (int sub = 0; sub < 2; ++sub) {
            int d = d0 + sub * 32 + l31;
#pragma unroll
            for (int r = 0; r < 16; ++r) {
                int row = (r & 3) + 8 * (r >> 2) + 4 * half;
                int R = r0 + row;
                if (R < R_) inflh[(size_t)R * D_ + d] = to_bf16(acc2[sub][r]);
            }
        }
    }
}

// ---------------------------------------------------------------------------
// combine: block-level 1-D convolution. Block = 16 outputs x 512-dim half.
// Interior: load 23 rows ONCE each, scatter into 16 accumulators.
// grid = B_ * 128 * 2 = 1024.
// ---------------------------------------------------------------------------
__global__ __launch_bounds__(256) void combine_kernel(const float* __restrict__ magw,
                                                      const unsigned short* __restrict__ normh,
                                                      const unsigned short* __restrict__ inflh,
                                                      float* __restrict__ out) {
    int blk = blockIdx.x;
    int half = blk & 1;
    int rest = blk >> 1;
    int b = rest >> 7;
    int s0 = (rest & 127) * 16;
    int tid = threadIdx.x;
    int d = half * 512 + tid * 2;
    size_t rbase = (size_t)b * T_;
    const float C = 0.9f / 7.0f;

    if (s0 != 0) {
        float2 acc[16]; float ws[16];
#pragma unroll
        for (int i = 0; i < 16; ++i) { acc[i] = make_float2(0.f, 0.f); ws[i] = 0.f; }
#pragma unroll
        for (int i2 = 0; i2 < 23; ++i2) {
            int t = s0 - 8 + i2;
            size_t off = (rbase + t) * D_ + d;
            ushort2 n2 = *(const ushort2*)(normh + off);
            ushort2 v2 = *(const ushort2*)(inflh + off);
            float m = magw[rbase + t];
            float2 vm = make_float2(m * (0.6f * fb(n2.x) + 0.4f * fb(v2.x)),
                                    m * (0.6f * fb(n2.y) + 0.4f * fb(v2.y)));
#pragma unroll
            for (int j = 0; j < 8; ++j) {
                int idx = i2 - j;
                if (idx >= 0 && idx < 16) {
                    float lin = 0.1f + C * (float)j;
                    acc[idx].x += lin * vm.x;
                    acc[idx].y += lin * vm.y;
                    ws[idx] += lin * m;
                }
            }
        }
#pragma unroll
        for (int i = 0; i < 16; ++i) {
            float r = 1.0f / fmaxf(ws[i], 1e-8f);
            *(float2*)&out[((size_t)b * S_ + s0 + i) * D_ + d] =
                make_float2(acc[i].x * r, acc[i].y * r);
        }
    } else {
        for (int i = 0; i < 16; ++i) {
            int s = i;
            int w = (s < 8) ? s : 8;
            float rw = (w > 1) ? 0.9f / (float)(w - 1) : 0.0f;
            float2 acc = make_float2(0.f, 0.f); float wsum = 0.f;
            for (int j = 0; j < w; ++j) {
                int t = s - w + j;
                float m = magw[rbase + t];
                float wt = (0.1f + rw * (float)j) * m;
                size_t off = (rbase + t) * D_ + d;
                ushort2 n2 = *(const ushort2*)(normh + off);
                ushort2 v2 = *(const ushort2*)(inflh + off);
                acc.x += wt * (0.6f * fb(n2.x) + 0.4f * fb(v2.x));
                acc.y += wt * (0.6f * fb(n2.y) + 0.4f * fb(v2.y));
                wsum += wt;
            }
            float r = 1.0f / fmaxf(wsum, 1e-8f);
            *(float2*)&out[((size_t)b * S_ + s) * D_ + d] =
                make_float2(acc.x * r, acc.y * r);
        }
    }
}

// ---------------------------------------------------------------------------
extern "C" void kernel_launch(void* const* d_in, const int* in_sizes, int n_in,
                              void* d_out, int out_size, void* d_ws, size_t ws_size,
                              hipStream_t stream) {
    const float* emb  = (const float*)d_in[0];
    const float* guid = (const float*)d_in[1];
    float* out = (float*)d_out;
    char* ws = (char*)d_ws;

    float*  rg2   = (float*)(ws + WSOFF_RG2);
    float*  magw  = (float*)(ws + WSOFF_MAGW);
    short8* Bp1   = (short8*)(ws + WSOFF_BP1);
    short8* Bp2   = (short8*)(ws + WSOFF_BP2);
    short*  normh = (short*)(ws + WSOFF_NH);
    short*  inflh = (short*)(ws + WSOFF_IH);

    prep_kernel<<<384, 256, 0, stream>>>(guid, rg2, Bp1, Bp2);
    fused_kernel<<<RPAD / MT, 1024, LDS_TOTAL, stream>>>(emb, Bp1, Bp2, rg2, magw, normh, inflh);
    combine_kernel<<<B_ * 128 * 2, 256, 0, stream>>>(magw, (const unsigned short*)normh,
                                                     (const unsigned short*)inflh, out);
}

// Round 8
// 145.745 us; speedup vs baseline: 1.0193x; 1.0193x over previous
//
#include <hip/hip_runtime.h>
#include <math.h>

// Dims fixed by reference setup_inputs
#define B_ 4
#define S_ 2048
#define D_ 1024
#define G_ 512
#define T_ 2047          // diff rows per batch
#define R_ 8188          // B_*T_ valid rows
#define RPAD 8192
#define MT 32            // diff rows per fused block
#define CBST 136         // chunk LDS row stride (shorts): 128 + 8
#define AST2 520         // weights LDS row stride (shorts): 512 + 8

typedef __attribute__((ext_vector_type(8))) short short8;
typedef __attribute__((ext_vector_type(4))) short s16x4;
typedef __attribute__((ext_vector_type(4))) float f32x4;

// ws byte offsets
#define WSOFF_RG2  0u           // 512 f
#define WSOFF_MAGW 2048u        // 8192 f
#define WSOFF_BP1  34816u       // Bpack1 [128][512] short8 (1 MB)
#define WSOFF_BP2  1083392u     // Bpack2 [64][1024] short8 (1 MB)
#define WSOFF_DH   2131968u     // diffh (RAW diffs) [8192][1024] bf16 (16 MB)
#define WSOFF_IH   18909184u    // inflh [8192][1024] bf16 (16 MB)
#define WSOFF_PM   35686400u    // premul = 0.6*rmag [8192] f (32 KB)

// dynamic LDS layout (bytes)
#define LDS_CB    0u            // chunkbuf[2][32][136] shorts = 34816 B (aliased by weights)
#define LDS_RG2   34816u        // 512 f
#define LDS_PRED  36864u        // 32*16 f
#define LDS_SS    38912u        // 32 f
#define LDS_RMG   39040u        // 32 f
#define LDS_RMX   39168u        // 32 f
#define LDS_RRS   39296u        // 32 f
#define LDS_TOTAL 39424u

__device__ inline short to_bf16(float f) {
    union { float f; unsigned u; } v; v.f = f;
    unsigned r = v.u + 0x7fffu + ((v.u >> 16) & 1u);
    return (short)(r >> 16);
}
__device__ inline float fb(unsigned short h) {
    union { unsigned u; float f; } v;
    v.u = ((unsigned)h) << 16;
    return v.f;
}

// ---------------------------------------------------------------------------
// prep: blocks 0..127  -> rg2 + Bpack1; blocks 128..383 -> Bpack2
// ---------------------------------------------------------------------------
__global__ __launch_bounds__(256) void prep_kernel(const float* __restrict__ guid,
                                                   float* __restrict__ rg2,
                                                   short8* __restrict__ Bp1,
                                                   short8* __restrict__ Bp2) {
    int blk = blockIdx.x, tid = threadIdx.x;
    if (blk < 128) {
        int g = blk * 4 + (tid >> 6);
        int lane = tid & 63;
        const float4* gp = (const float4*)(guid + (size_t)g * D_);
        float ss = 0.f;
#pragma unroll
        for (int i = 0; i < 4; ++i) {
            float4 v = gp[lane + 64 * i];
            ss += v.x * v.x + v.y * v.y + v.z * v.z + v.w * v.w;
        }
#pragma unroll
        for (int m = 32; m >= 1; m >>= 1) ss += __shfl_xor(ss, m, 64);
        if (lane == 0) rg2[g] = 2.0f / fmaxf(sqrtf(ss), 1e-8f);
#pragma unroll
        for (int h = 0; h < 2; ++h) {
            int kg = lane + 64 * h;
            const float* src = guid + (size_t)g * D_ + kg * 8;
            short8 v;
#pragma unroll
            for (int j = 0; j < 8; ++j) v[j] = to_bf16(src[j]);
            Bp1[(size_t)kg * G_ + g] = v;
        }
    } else {
        int idx = blk - 128;
        int gg = idx >> 2;
        int d = (idx & 3) * 256 + tid;
        short8 v;
#pragma unroll
        for (int j = 0; j < 8; ++j) v[j] = to_bf16(guid[(size_t)(gg * 8 + j) * D_ + d]);
        Bp2[(size_t)gg * D_ + d] = v;
    }
}

// ---------------------------------------------------------------------------
// fused: 32-row tile, 16 waves, 16x16x32 MFMA.
// gemm1 runs on RAW diffs, K-chunked (8 x 128) with double-buffered LDS A so
// emb HBM loads overlap MFMA+B-stream. Normalization deferred into softmax:
// e = exp(rmag*(u - umax)), u = dot_raw * rg2.  diffh stores raw diffs;
// premul = 0.6*rmag is folded into combine.
// ---------------------------------------------------------------------------
__global__ __launch_bounds__(1024, 4) void fused_kernel(const float* __restrict__ emb,
                                                        const short8* __restrict__ Bp1,
                                                        const short8* __restrict__ Bp2,
                                                        const float* __restrict__ rg2,
                                                        float* __restrict__ magw,
                                                        float* __restrict__ premul,
                                                        short* __restrict__ diffh,
                                                        short* __restrict__ inflh) {
    extern __shared__ char smem[];
    short* cb0  = (short*)(smem + LDS_CB);            // chunk buf 0: [32][136]
    short* cb1  = cb0 + 32 * CBST;                    // chunk buf 1
    short* WBs  = (short*)(smem + LDS_CB);            // weights [32][520], aliased
    float* rg2s = (float*)(smem + LDS_RG2);
    float* pred = (float*)(smem + LDS_PRED);          // [32][16]
    float* ssr  = (float*)(smem + LDS_SS);
    float* rmg  = (float*)(smem + LDS_RMG);
    float* rmxu = (float*)(smem + LDS_RMX);
    float* rrs  = (float*)(smem + LDS_RRS);

    const int tid = threadIdx.x;
    const int wave = tid >> 6, lane = tid & 63;
    const int l15 = lane & 15, quad = lane >> 4;
    const int r0 = blockIdx.x * MT;

    // staging identity: 32 rows x 32 segments of 4 k
    const int srow = tid >> 5;
    const int seg  = tid & 31;
    const int Rrow = r0 + srow;
    const bool rvalid = (Rrow < R_);
    int bb = Rrow / T_;
    int tt = Rrow - bb * T_;
    const float4* p0 = (const float4*)(emb + ((size_t)bb * S_ + tt) * D_);
    const float4* p1 = p0 + (D_ / 4);
    short* dh = diffh + (size_t)Rrow * D_;
    float ssacc = 0.f;

    // ---- stage chunk 0 ----
    {
        float4 dv = make_float4(0.f, 0.f, 0.f, 0.f);
        if (rvalid) {
            float4 x0 = p0[seg], x1 = p1[seg];
            dv = make_float4(x1.x - x0.x, x1.y - x0.y, x1.z - x0.z, x1.w - x0.w);
            ssacc += dv.x * dv.x + dv.y * dv.y + dv.z * dv.z + dv.w * dv.w;
        }
        s16x4 h;
        h[0] = to_bf16(dv.x); h[1] = to_bf16(dv.y); h[2] = to_bf16(dv.z); h[3] = to_bf16(dv.w);
        *(s16x4*)&cb0[srow * CBST + seg * 4] = h;
        if (rvalid) *(s16x4*)(dh + seg * 4) = h;
    }
    if (tid < G_) rg2s[tid] = rg2[tid];
    __syncthreads();

    // ---- gemm1 with chunked A pipeline; wave owns g in [32w, 32w+32) ----
    f32x4 acc1[2][2];
#pragma unroll
    for (int mt = 0; mt < 2; ++mt)
#pragma unroll
        for (int nt = 0; nt < 2; ++nt) acc1[mt][nt] = (f32x4)0.f;
    {
        const int g0 = wave * 32;
        const short8* Bb = Bp1 + (size_t)quad * G_ + g0 + l15;
        short8 bc0 = Bb[0], bc1 = Bb[16], bn0, bn1;
#pragma unroll
        for (int c = 0; c < 8; ++c) {
            const short* cbr = (c & 1) ? cb1 : cb0;
            short* cbw = (c & 1) ? cb0 : cb1;
            // issue next chunk's HBM loads early (overlap with MFMAs below)
            float4 x0n, x1n;
            if (c < 7 && rvalid) {
                x0n = p0[(c + 1) * 32 + seg];
                x1n = p1[(c + 1) * 32 + seg];
            }
#pragma unroll
            for (int ksl = 0; ksl < 4; ++ksl) {
                int ks = c * 4 + ksl;
                if (ks < 63) {
                    const short8* Bx = Bb + (size_t)(ks + 1) * 4 * G_;
                    bn0 = Bx[0]; bn1 = Bx[16];
                }
                short8 a0 = *(const short8*)&cbr[l15 * CBST + ksl * 32 + quad * 8];
                short8 a1 = *(const short8*)&cbr[(16 + l15) * CBST + ksl * 32 + quad * 8];
                acc1[0][0] = __builtin_amdgcn_mfma_f32_16x16x32_bf16(a0, bc0, acc1[0][0], 0, 0, 0);
                acc1[0][1] = __builtin_amdgcn_mfma_f32_16x16x32_bf16(a0, bc1, acc1[0][1], 0, 0, 0);
                acc1[1][0] = __builtin_amdgcn_mfma_f32_16x16x32_bf16(a1, bc0, acc1[1][0], 0, 0, 0);
                acc1[1][1] = __builtin_amdgcn_mfma_f32_16x16x32_bf16(a1, bc1, acc1[1][1], 0, 0, 0);
                bc0 = bn0; bc1 = bn1;
            }
            if (c < 7) {
                float4 dv = make_float4(0.f, 0.f, 0.f, 0.f);
                if (rvalid) {
                    dv = make_float4(x1n.x - x0n.x, x1n.y - x0n.y,
                                     x1n.z - x0n.z, x1n.w - x0n.w);
                    ssacc += dv.x * dv.x + dv.y * dv.y + dv.z * dv.z + dv.w * dv.w;
                }
                s16x4 h;
                h[0] = to_bf16(dv.x); h[1] = to_bf16(dv.y);
                h[2] = to_bf16(dv.z); h[3] = to_bf16(dv.w);
                *(s16x4*)&cbw[srow * CBST + seg * 4] = h;
                if (rvalid) *(s16x4*)(dh + (c + 1) * 128 + seg * 4) = h;
            }
            __syncthreads();
        }
    }

    // ---- softmax with deferred normalization ----
    {
        const int g0 = wave * 32;
        // finish row sums-of-squares (32-lane halves hold one row each)
        float ssv = ssacc;
#pragma unroll
        for (int m = 16; m >= 1; m >>= 1) ssv += __shfl_xor(ssv, m, 64);
        if ((lane & 31) == 0) ssr[srow] = ssv;

        // u = dot_raw * rg2; per-wave max over its 32 g
        float pmax[2][4];
#pragma unroll
        for (int mt = 0; mt < 2; ++mt)
#pragma unroll
            for (int r2 = 0; r2 < 4; ++r2) pmax[mt][r2] = -1e30f;
#pragma unroll
        for (int mt = 0; mt < 2; ++mt)
#pragma unroll
            for (int nt = 0; nt < 2; ++nt) {
                float rgv = rg2s[g0 + nt * 16 + l15];
#pragma unroll
                for (int r2 = 0; r2 < 4; ++r2) {
                    float u = acc1[mt][nt][r2] * rgv;
                    acc1[mt][nt][r2] = u;
                    pmax[mt][r2] = fmaxf(pmax[mt][r2], u);
                }
            }
#pragma unroll
        for (int m = 8; m >= 1; m >>= 1)
#pragma unroll
            for (int mt = 0; mt < 2; ++mt)
#pragma unroll
                for (int r2 = 0; r2 < 4; ++r2)
                    pmax[mt][r2] = fmaxf(pmax[mt][r2], __shfl_xor(pmax[mt][r2], m, 16));
        if (l15 == 0) {
#pragma unroll
            for (int mt = 0; mt < 2; ++mt)
#pragma unroll
                for (int r2 = 0; r2 < 4; ++r2)
                    pred[(mt * 16 + quad * 4 + r2) * 16 + wave] = pmax[mt][r2];
        }
        __syncthreads();
        if (tid < MT) {
            float sv = ssr[tid];
            float mag = sqrtf(sv);
            float rm = (mag > 1e-6f) ? (1.0f / mag) : 0.0f;
            rmg[tid] = rm;
            int RR = r0 + tid;
            if (RR < R_) { magw[RR] = tanhf(2.0f * mag); premul[RR] = 0.6f * rm; }
            float mx = pred[tid * 16];
#pragma unroll
            for (int w2 = 1; w2 < 16; ++w2) mx = fmaxf(mx, pred[tid * 16 + w2]);
            rmxu[tid] = mx;
        }
        __syncthreads();
        // e = exp(rmag * (u - umax))
        float psum[2][4];
#pragma unroll
        for (int mt = 0; mt < 2; ++mt)
#pragma unroll
            for (int r2 = 0; r2 < 4; ++r2) psum[mt][r2] = 0.f;
#pragma unroll
        for (int mt = 0; mt < 2; ++mt)
#pragma unroll
            for (int nt = 0; nt < 2; ++nt)
#pragma unroll
                for (int r2 = 0; r2 < 4; ++r2) {
                    int row = mt * 16 + quad * 4 + r2;
                    float e = __expf(rmg[row] * (acc1[mt][nt][r2] - rmxu[row]));
                    acc1[mt][nt][r2] = e;
                    psum[mt][r2] += e;
                }
#pragma unroll
        for (int m = 8; m >= 1; m >>= 1)
#pragma unroll
            for (int mt = 0; mt < 2; ++mt)
#pragma unroll
                for (int r2 = 0; r2 < 4; ++r2)
                    psum[mt][r2] += __shfl_xor(psum[mt][r2], m, 16);
        if (l15 == 0) {
#pragma unroll
            for (int mt = 0; mt < 2; ++mt)
#pragma unroll
                for (int r2 = 0; r2 < 4; ++r2)
                    pred[(mt * 16 + quad * 4 + r2) * 16 + wave] = psum[mt][r2];
        }
        __syncthreads();
        if (tid < MT) {
            float s = 0.f;
#pragma unroll
            for (int w2 = 0; w2 < 16; ++w2) s += pred[tid * 16 + w2];
            rrs[tid] = 1.0f / s;
        }
        __syncthreads();
#pragma unroll
        for (int mt = 0; mt < 2; ++mt)
#pragma unroll
            for (int nt = 0; nt < 2; ++nt)
#pragma unroll
                for (int r2 = 0; r2 < 4; ++r2) {
                    int row = mt * 16 + quad * 4 + r2;
                    WBs[row * AST2 + g0 + nt * 16 + l15] =
                        to_bf16(acc1[mt][nt][r2] * rrs[row]);
                }
    }
    __syncthreads();

    // ---- gemm2: wave owns d in [64w, 64w+64) ----
    f32x4 acc2[2][4];
#pragma unroll
    for (int mt = 0; mt < 2; ++mt)
#pragma unroll
        for (int nt = 0; nt < 4; ++nt) acc2[mt][nt] = (f32x4)0.f;
    {
        const short8* Bb = Bp2 + (size_t)quad * D_ + wave * 64 + l15;
        short8 bc[4], bn[4];
#pragma unroll
        for (int nt = 0; nt < 4; ++nt) bc[nt] = Bb[nt * 16];
        for (int ks = 0; ks < 16; ++ks) {
            if (ks < 15) {
                const short8* Bx = Bb + (size_t)(ks + 1) * 4 * D_;
#pragma unroll
                for (int nt = 0; nt < 4; ++nt) bn[nt] = Bx[nt * 16];
            }
            short8 a0 = *(const short8*)&WBs[l15 * AST2 + ks * 32 + quad * 8];
            short8 a1 = *(const short8*)&WBs[(16 + l15) * AST2 + ks * 32 + quad * 8];
#pragma unroll
            for (int nt = 0; nt < 4; ++nt) {
                acc2[0][nt] = __builtin_amdgcn_mfma_f32_16x16x32_bf16(a0, bc[nt], acc2[0][nt], 0, 0, 0);
                acc2[1][nt] = __builtin_amdgcn_mfma_f32_16x16x32_bf16(a1, bc[nt], acc2[1][nt], 0, 0, 0);
            }
#pragma unroll
            for (int nt = 0; nt < 4; ++nt) bc[nt] = bn[nt];
        }
    }

    // ---- influence bf16 out ----
#pragma unroll
    for (int mt = 0; mt < 2; ++mt)
#pragma unroll
        for (int nt = 0; nt < 4; ++nt) {
            int d = wave * 64 + nt * 16 + l15;
#pragma unroll
            for (int r2 = 0; r2 < 4; ++r2) {
                int R = r0 + mt * 16 + quad * 4 + r2;
                if (R < R_) inflh[(size_t)R * D_ + d] = to_bf16(acc2[mt][nt][r2]);
            }
        }
}

// ---------------------------------------------------------------------------
// combine: block-level 1-D convolution on raw diffs.
// blend = premul[t]*diff + 0.4*infl.  Block = 16 outputs x 512-dim half.
// ---------------------------------------------------------------------------
__global__ __launch_bounds__(256) void combine_kernel(const float* __restrict__ magw,
                                                      const float* __restrict__ premul,
                                                      const unsigned short* __restrict__ diffh,
                                                      const unsigned short* __restrict__ inflh,
                                                      float* __restrict__ out) {
    int blk = blockIdx.x;
    int half = blk & 1;
    int rest = blk >> 1;
    int b = rest >> 7;
    int s0 = (rest & 127) * 16;
    int tid = threadIdx.x;
    int d = half * 512 + tid * 2;
    size_t rbase = (size_t)b * T_;
    const float C = 0.9f / 7.0f;

    if (s0 != 0) {
        float2 acc[16]; float ws[16];
#pragma unroll
        for (int i = 0; i < 16; ++i) { acc[i] = make_float2(0.f, 0.f); ws[i] = 0.f; }
#pragma unroll
        for (int i2 = 0; i2 < 23; ++i2) {
            int t = s0 - 8 + i2;
            size_t off = (rbase + t) * D_ + d;
            ushort2 n2 = *(const ushort2*)(diffh + off);
            ushort2 v2 = *(const ushort2*)(inflh + off);
            float m = magw[rbase + t];
            float pm = premul[rbase + t];
            float2 vm = make_float2(m * (pm * fb(n2.x) + 0.4f * fb(v2.x)),
                                    m * (pm * fb(n2.y) + 0.4f * fb(v2.y)));
#pragma unroll
            for (int j = 0; j < 8; ++j) {
                int idx = i2 - j;
                if (idx >= 0 && idx < 16) {
                    float lin = 0.1f + C * (float)j;
                    acc[idx].x += lin * vm.x;
                    acc[idx].y += lin * vm.y;
                    ws[idx] += lin * m;
                }
            }
        }
#pragma unroll
        for (int i = 0; i < 16; ++i) {
            float r = 1.0f / fmaxf(ws[i], 1e-8f);
            *(float2*)&out[((size_t)b * S_ + s0 + i) * D_ + d] =
                make_float2(acc[i].x * r, acc[i].y * r);
        }
    } else {
        for (int i = 0; i < 16; ++i) {
            int s = i;
            int w = (s < 8) ? s : 8;
            float rw = (w > 1) ? 0.9f / (float)(w - 1) : 0.0f;
            float2 acc = make_float2(0.f, 0.f); float wsum = 0.f;
            for (int j = 0; j < w; ++j) {
                int t = s - w + j;
                float m = magw[rbase + t];
                float pm = premul[rbase + t];
                float wt = (0.1f + rw * (float)j) * m;
                size_t off = (rbase + t) * D_ + d;
                ushort2 n2 = *(const ushort2*)(diffh + off);
                ushort2 v2 = *(const ushort2*)(inflh + off);
                acc.x += wt * (pm * fb(n2.x) + 0.4f * fb(v2.x));
                acc.y += wt * (pm * fb(n2.y) + 0.4f * fb(v2.y));
                wsum += wt;
            }
            float r = 1.0f / fmaxf(wsum, 1e-8f);
            *(float2*)&out[((size_t)b * S_ + s) * D_ + d] =
                make_float2(acc.x * r, acc.y * r);
        }
    }
}

// ---------------------------------------------------------------------------
extern "C" void kernel_launch(void* const* d_in, const int* in_sizes, int n_in,
                              void* d_out, int out_size, void* d_ws, size_t ws_size,
                              hipStream_t stream) {
    const float* emb  = (const float*)d_in[0];
    const float* guid = (const float*)d_in[1];
    float* out = (float*)d_out;
    char* ws = (char*)d_ws;

    float*  rg2    = (float*)(ws + WSOFF_RG2);
    float*  magw   = (float*)(ws + WSOFF_MAGW);
    short8* Bp1    = (short8*)(ws + WSOFF_BP1);
    short8* Bp2    = (short8*)(ws + WSOFF_BP2);
    short*  diffh  = (short*)(ws + WSOFF_DH);
    short*  inflh  = (short*)(ws + WSOFF_IH);
    float*  premul = (float*)(ws + WSOFF_PM);

    prep_kernel<<<384, 256, 0, stream>>>(guid, rg2, Bp1, Bp2);
    fused_kernel<<<RPAD / MT, 1024, LDS_TOTAL, stream>>>(emb, Bp1, Bp2, rg2, magw,
                                                         premul, diffh, inflh);
    combine_kernel<<<B_ * 128 * 2, 256, 0, stream>>>(magw, premul,
                                                     (const unsigned short*)diffh,
                                                     (const unsigned short*)inflh, out);
}